// Round 3
// baseline (300.125 us; speedup 1.0000x reference)
//
#include <hip/hip_runtime.h>
#include <cstdint>
#include <cstddef>

// Fused prefix-LM self-attention, B=8192, S=64, D=32, H=4, DH=8, all f32.
// Block = 128 threads = 2 waves = 1 batch item; lane = sequence row.
// Wave w owns heads {2w,2w+1}: computes q/k/v dims 16w..16w+15, streams
// its 2 heads in the j-loop, then a 16-dim partial of the out-projection;
// partials reduced through LDS, final store fully coalesced via LDS.
// Weights via wave-uniform scalar loads (SGPRs). k,v in LDS with XOR
// chunk swizzle. Streaming softmax (no max subtraction; |score|<~2).
#define NB 8192
#define NS 64
#define ND 32

__global__ __launch_bounds__(128, 4) void fused_prefix_attn(
    const float* __restrict__ x,
    const int*   __restrict__ aatt,
    const float* __restrict__ Wq, const float* __restrict__ bq,
    const float* __restrict__ Wk, const float* __restrict__ bk,
    const float* __restrict__ Wv, const float* __restrict__ bv,
    const float* __restrict__ Wp, const float* __restrict__ bp,
    float* __restrict__ out)
{
    __shared__ float kl[NS][ND];   // 8 KiB
    __shared__ float vl[NS][ND];   // 8 KiB

    const int tid  = threadIdx.x;
    const int w    = tid >> 6;     // wave 0/1: heads {2w,2w+1}, dims 16w..16w+15
    const int lane = tid & 63;     // query row
    const int b    = blockIdx.x;

    const size_t rowoff = ((size_t)b * NS + lane) * ND;

    // ---- load x row (both waves load the same row; L1/L2 absorbs) ----
    float xr[ND];
#pragma unroll
    for (int c = 0; c < ND / 4; ++c) {
        float4 t = reinterpret_cast<const float4*>(x + rowoff)[c];
        xr[4*c+0] = t.x; xr[4*c+1] = t.y; xr[4*c+2] = t.z; xr[4*c+3] = t.w;
    }

    // ---- q/k/v projections: this wave's 16 output dims ----
    float qr[16];
#pragma unroll
    for (int cc = 0; cc < 4; ++cc) {
        const int o0 = 16*w + 4*cc;          // wave-uniform
        float aq[4], ak[4], av[4];
#pragma unroll
        for (int i = 0; i < 4; ++i) {
            aq[i] = bq[o0+i]; ak[i] = bk[o0+i]; av[i] = bv[o0+i];
        }
#pragma unroll
        for (int d = 0; d < ND; ++d) {
            const float xv = xr[d];
#pragma unroll
            for (int i = 0; i < 4; ++i) {
                aq[i] = fmaf(xv, Wq[(o0+i)*ND + d], aq[i]);
                ak[i] = fmaf(xv, Wk[(o0+i)*ND + d], ak[i]);
                av[i] = fmaf(xv, Wv[(o0+i)*ND + d], av[i]);
            }
        }
#pragma unroll
        for (int i = 0; i < 4; ++i) qr[4*cc+i] = aq[i];
        // XOR-swizzled float4 store: global chunk c -> slot c^(lane&7)
        const int c  = 4*w + cc;
        const int cs = c ^ (lane & 7);
        float4 kt; kt.x = ak[0]; kt.y = ak[1]; kt.z = ak[2]; kt.w = ak[3];
        float4 vt; vt.x = av[0]; vt.y = av[1]; vt.z = av[2]; vt.w = av[3];
        *reinterpret_cast<float4*>(&kl[lane][4*cs]) = kt;
        *reinterpret_cast<float4*>(&vl[lane][4*cs]) = vt;
    }

    // fold 1/sqrt(8)*log2(e) into q so the j-loop does exp2f(s) directly
    const float escale = 0.35355339059327373f * 1.4426950408889634f;
#pragma unroll
    for (int i = 0; i < 16; ++i) qr[i] *= escale;

    __syncthreads();

    const int aab = aatt[b];   // prefix length for this batch

    // ---- streaming attention over keys, 2 heads per wave ----
    float sum[2] = {0.f, 0.f};
    float oh[2][8] = {};

#pragma unroll 8                 // keeps (j&7) a compile-time constant
    for (int j = 0; j < NS; ++j) {
        const bool allowed_pref = (j < aab);
        float e[2];
#pragma unroll
        for (int hl = 0; hl < 2; ++hl) {
            const int h = 2*w + hl;
            const float4 ka = *reinterpret_cast<const float4*>(&kl[j][4*((2*h  ) ^ (j & 7))]);
            const float4 kb = *reinterpret_cast<const float4*>(&kl[j][4*((2*h+1) ^ (j & 7))]);
            float s;
            s = qr[8*hl+0] * ka.x;
            s = fmaf(qr[8*hl+1], ka.y, s);
            s = fmaf(qr[8*hl+2], ka.z, s);
            s = fmaf(qr[8*hl+3], ka.w, s);
            s = fmaf(qr[8*hl+4], kb.x, s);
            s = fmaf(qr[8*hl+5], kb.y, s);
            s = fmaf(qr[8*hl+6], kb.z, s);
            s = fmaf(qr[8*hl+7], kb.w, s);
            float ee = exp2f(s);
            ee = (j <= lane || allowed_pref) ? ee : 0.0f;
            e[hl] = ee;
            sum[hl] += ee;
        }
#pragma unroll
        for (int hl = 0; hl < 2; ++hl) {
            const int h = 2*w + hl;
            const float4 va = *reinterpret_cast<const float4*>(&vl[j][4*((2*h  ) ^ (j & 7))]);
            const float4 vb = *reinterpret_cast<const float4*>(&vl[j][4*((2*h+1) ^ (j & 7))]);
            const float p = e[hl];
            oh[hl][0] = fmaf(p, va.x, oh[hl][0]);
            oh[hl][1] = fmaf(p, va.y, oh[hl][1]);
            oh[hl][2] = fmaf(p, va.z, oh[hl][2]);
            oh[hl][3] = fmaf(p, va.w, oh[hl][3]);
            oh[hl][4] = fmaf(p, vb.x, oh[hl][4]);
            oh[hl][5] = fmaf(p, vb.y, oh[hl][5]);
            oh[hl][6] = fmaf(p, vb.z, oh[hl][6]);
            oh[hl][7] = fmaf(p, vb.w, oh[hl][7]);
        }
    }

    // normalized attention output for this wave's 16 dims
    float oacc[16];
#pragma unroll
    for (int hl = 0; hl < 2; ++hl) {
        const float inv = 1.0f / sum[hl];
#pragma unroll
        for (int d = 0; d < 8; ++d) oacc[8*hl+d] = oh[hl][d] * inv;
    }

    __syncthreads();   // all j-loop reads of kl/vl complete before reuse

    // ---- out-projection partial over this wave's 16 dims ----
    float po[ND];
#pragma unroll
    for (int cc = 0; cc < 8; ++cc) {
        float ao[4] = {0.f, 0.f, 0.f, 0.f};
#pragma unroll
        for (int i = 0; i < 16; ++i) {
            const float ov = oacc[i];
#pragma unroll
            for (int t = 0; t < 4; ++t)
                ao[t] = fmaf(ov, Wp[(4*cc+t)*ND + 16*w + i], ao[t]);
        }
#pragma unroll
        for (int t = 0; t < 4; ++t) po[4*cc+t] = ao[t];
    }

    if (w == 0) {      // wave0 partial -> LDS (swizzled)
#pragma unroll
        for (int cc = 0; cc < 8; ++cc) {
            const int cs = cc ^ (lane & 7);
            float4 t; t.x = po[4*cc+0]; t.y = po[4*cc+1]; t.z = po[4*cc+2]; t.w = po[4*cc+3];
            *reinterpret_cast<float4*>(&kl[lane][4*cs]) = t;
        }
    }
    __syncthreads();
    if (w == 1) {      // wave1: add partials + bias, final rows -> LDS
#pragma unroll
        for (int cc = 0; cc < 8; ++cc) {
            const int cs = cc ^ (lane & 7);
            float4 p0 = *reinterpret_cast<const float4*>(&kl[lane][4*cs]);
            float4 t;
            t.x = po[4*cc+0] + p0.x + bp[4*cc+0];
            t.y = po[4*cc+1] + p0.y + bp[4*cc+1];
            t.z = po[4*cc+2] + p0.z + bp[4*cc+2];
            t.w = po[4*cc+3] + p0.w + bp[4*cc+3];
            *reinterpret_cast<float4*>(&vl[lane][4*cs]) = t;
        }
    }
    __syncthreads();

    // ---- fully coalesced store: 512 float4s by 128 threads ----
    float4* outb = reinterpret_cast<float4*>(out + (size_t)b * NS * ND);
#pragma unroll
    for (int m = 0; m < 4; ++m) {
        const int f   = m * 128 + tid;
        const int row = f >> 3;
        const int c   = f & 7;
        const int cs  = c ^ (row & 7);
        outb[f] = *reinterpret_cast<const float4*>(&vl[row][4*cs]);
    }
}

extern "C" void kernel_launch(void* const* d_in, const int* in_sizes, int n_in,
                              void* d_out, int out_size, void* d_ws, size_t ws_size,
                              hipStream_t stream) {
    const float* x  = (const float*)d_in[0];
    const int*   aa = (const int*)d_in[1];
    const float* Wq = (const float*)d_in[2];
    const float* bq = (const float*)d_in[3];
    const float* Wk = (const float*)d_in[4];
    const float* bk = (const float*)d_in[5];
    const float* Wv = (const float*)d_in[6];
    const float* bv = (const float*)d_in[7];
    const float* Wp = (const float*)d_in[8];
    const float* bp = (const float*)d_in[9];
    float* out = (float*)d_out;

    dim3 grid(NB), block(128);
    hipLaunchKernelGGL(fused_prefix_attn, grid, block, 0, stream,
                       x, aa, Wq, bq, Wk, bk, Wv, bv, Wp, bp, out);
}

// Round 4
// 126.939 us; speedup vs baseline: 2.3643x; 2.3643x over previous
//
#include <hip/hip_runtime.h>
#include <cstdint>
#include <cstddef>

// Fused prefix-LM self-attention, B=8192, S=64, D=32, H=4, DH=8.
// bf16 MFMA (16x16x32) end-to-end: Q^T/K^T via mfma(W,X) kept in registers
// as packed bf16 (fragments built with ds_bpermute), V and P staged in
// small padded wave-private LDS (no __syncthreads anywhere).
// Softmax: swapped scores S^T = K@Q^T, streaming (no max subtraction,
// |score|<~2), col-sums via 2x shfl_xor. Out-projection accumulated
// per-head with zero-masked Wp fragments. All f32 accumulation.
#define NB 8192

typedef __attribute__((ext_vector_type(8))) short short8;
typedef __attribute__((ext_vector_type(4))) float f32x4;

union S8U { short8 s; unsigned u[4]; uint4 v; };

static __device__ __forceinline__ unsigned short f2bf(float f) {
    union { float f; unsigned u; } v; v.f = f;
    unsigned r = v.u + 0x7FFFu + ((v.u >> 16) & 1u);   // round-nearest-even
    return (unsigned short)(r >> 16);
}
static __device__ __forceinline__ unsigned pk2(float a, float b) {
    return (unsigned)f2bf(a) | ((unsigned)f2bf(b) << 16);
}

#define MFMA __builtin_amdgcn_mfma_f32_16x16x32_bf16
#define BPERM __builtin_amdgcn_ds_bpermute

__global__ __launch_bounds__(128) void fused_attn_mfma(
    const float* __restrict__ x,
    const int*   __restrict__ aatt,
    const float* __restrict__ Wq, const float* __restrict__ bq,
    const float* __restrict__ Wk, const float* __restrict__ bk,
    const float* __restrict__ Wv, const float* __restrict__ bv,
    const float* __restrict__ Wp, const float* __restrict__ bp,
    float* __restrict__ out)
{
    // wave-private LDS (padded rows: 144B and 80B are 16B-multiples, bank-spread)
    __shared__ __align__(16) short vbt[2][32][72];   // V^T: [d][j], 2-wave
    __shared__ __align__(16) short psl[2][64][40];   // P slice: [i][j-local(32)]

    const int tid  = threadIdx.x;
    const int w    = tid >> 6;
    const int lane = tid & 63;
    const int q4   = lane >> 4;
    const int l15  = lane & 15;
    const int b    = blockIdx.x * 2 + w;

    const int aab   = aatt[b];
    const int bmask = (q4 == 0) ? -1 : 0;

    const int idxq[4] = { l15 * 4, (l15 + 16) * 4, (l15 + 32) * 4, (l15 + 48) * 4 };

    // ---- X fragments (A for V, B for Q^T/K^T): row = tile*16+l15, k = q4*8+e ----
    short8 xa[4];
    const float* xb = x + (size_t)b * 64 * 32;
#pragma unroll
    for (int nt = 0; nt < 4; ++nt) {
        const float* p = xb + (nt * 16 + l15) * 32 + q4 * 8;
        float4 u0 = *(const float4*)p;
        float4 u1 = *(const float4*)(p + 4);
        S8U t;
        t.u[0] = pk2(u0.x, u0.y); t.u[1] = pk2(u0.z, u0.w);
        t.u[2] = pk2(u1.x, u1.y); t.u[3] = pk2(u1.z, u1.w);
        xa[nt] = t.s;
    }
    // bias-column frag: 1.0 at k==32 (q4==0, e==0)
    S8U xo; xo.u[0] = (q4 == 0) ? 0x00003F80u : 0u; xo.u[1] = xo.u[2] = xo.u[3] = 0u;
    const short8 xone = xo.s;

    auto wrow = [&](const float* W, int row) -> short8 {
        const float* p = W + row * 32 + q4 * 8;
        float4 u0 = *(const float4*)p;
        float4 u1 = *(const float4*)(p + 4);
        S8U t;
        t.u[0] = pk2(u0.x, u0.y); t.u[1] = pk2(u0.z, u0.w);
        t.u[2] = pk2(u1.x, u1.y); t.u[3] = pk2(u1.z, u1.w);
        return t.s;
    };
    auto biasfrag = [&](const float* bb, int row) -> short8 {
        S8U t; t.u[0] = (q4 == 0) ? (unsigned)f2bf(bb[row]) : 0u;
        t.u[1] = t.u[2] = t.u[3] = 0u;
        return t.s;
    };

    const float escale = 0.35355339059327373f * 1.4426950408889634f; // 1/sqrt(8)*log2(e)

    // ---- Q^T, K^T projections -> packed bf16 register pairs ----
    unsigned qpk01[2][4], qpk23[2][4], kpk01[2][4], kpk23[2][4];
#pragma unroll
    for (int mt = 0; mt < 2; ++mt) {
        short8 wa = wrow(Wq, mt * 16 + l15);
        short8 wb = biasfrag(bq, mt * 16 + l15);
#pragma unroll
        for (int nt = 0; nt < 4; ++nt) {
            f32x4 acc = {0.f, 0.f, 0.f, 0.f};
            acc = MFMA(wa, xa[nt], acc, 0, 0, 0);
            acc = MFMA(wb, xone, acc, 0, 0, 0);
            qpk01[mt][nt] = pk2(acc[0] * escale, acc[1] * escale);
            qpk23[mt][nt] = pk2(acc[2] * escale, acc[3] * escale);
        }
    }
#pragma unroll
    for (int mt = 0; mt < 2; ++mt) {
        short8 wa = wrow(Wk, mt * 16 + l15);
        short8 wb = biasfrag(bk, mt * 16 + l15);
#pragma unroll
        for (int nt = 0; nt < 4; ++nt) {
            f32x4 acc = {0.f, 0.f, 0.f, 0.f};
            acc = MFMA(wa, xa[nt], acc, 0, 0, 0);
            acc = MFMA(wb, xone, acc, 0, 0, 0);
            kpk01[mt][nt] = pk2(acc[0], acc[1]);
            kpk23[mt][nt] = pk2(acc[2], acc[3]);
        }
    }
    // ---- V projection -> vbt[d][j] (V transposed) in LDS ----
#pragma unroll
    for (int nt = 0; nt < 2; ++nt) {
        short8 wv = wrow(Wv, nt * 16 + l15);
        const float bvv = bv[nt * 16 + l15];
#pragma unroll
        for (int mt = 0; mt < 4; ++mt) {
            f32x4 acc = {0.f, 0.f, 0.f, 0.f};
            acc = MFMA(xa[mt], wv, acc, 0, 0, 0);
            uint2 wv2;
            wv2.x = pk2(acc[0] + bvv, acc[1] + bvv);
            wv2.y = pk2(acc[2] + bvv, acc[3] + bvv);
            *(uint2*)&vbt[w][nt * 16 + l15][mt * 16 + q4 * 4] = wv2;
        }
    }

    // ---- head loop ----
    f32x4 yacc[4][2];
#pragma unroll
    for (int mt = 0; mt < 4; ++mt)
#pragma unroll
        for (int nt = 0; nt < 2; ++nt) yacc[mt][nt] = (f32x4){0.f, 0.f, 0.f, 0.f};

    const int iv[4] = { l15, 16 + l15, 32 + l15, 48 + l15 };

#pragma unroll
    for (int h = 0; h < 4; ++h) {
        const int mt = h >> 1;
        const int i0 = 2 * (h & 1);

        // scores B-frags (Q), zero for k>=8 (lanes q4!=0)
        short8 sqb[4];
#pragma unroll
        for (int it = 0; it < 4; ++it) {
            S8U t;
            t.u[0] = (unsigned)BPERM(idxq[i0],     (int)qpk01[mt][it]) & (unsigned)bmask;
            t.u[1] = (unsigned)BPERM(idxq[i0],     (int)qpk23[mt][it]) & (unsigned)bmask;
            t.u[2] = (unsigned)BPERM(idxq[i0 + 1], (int)qpk01[mt][it]) & (unsigned)bmask;
            t.u[3] = (unsigned)BPERM(idxq[i0 + 1], (int)qpk23[mt][it]) & (unsigned)bmask;
            sqb[it] = t.s;
        }
        // Wp head-slice B-frags, zero for k>=8
        short8 wpb[2];
#pragma unroll
        for (int nt = 0; nt < 2; ++nt) {
            const float* p = Wp + (nt * 16 + l15) * 32 + 8 * h;
            float4 u0 = *(const float4*)p;
            float4 u1 = *(const float4*)(p + 4);
            S8U t;
            t.u[0] = pk2(u0.x, u0.y) & (unsigned)bmask;
            t.u[1] = pk2(u0.z, u0.w) & (unsigned)bmask;
            t.u[2] = pk2(u1.x, u1.y) & (unsigned)bmask;
            t.u[3] = pk2(u1.z, u1.w) & (unsigned)bmask;
            wpb[nt] = t.s;
        }

        float csum[4] = {0.f, 0.f, 0.f, 0.f};
        f32x4 oacch[4];
#pragma unroll
        for (int it = 0; it < 4; ++it) oacch[it] = (f32x4){0.f, 0.f, 0.f, 0.f};

#pragma unroll
        for (int jb = 0; jb < 2; ++jb) {
            // scores A-frags (K rows)
            short8 ska[2];
#pragma unroll
            for (int jt = 0; jt < 2; ++jt) {
                const int jg = jb * 2 + jt;
                S8U t;
                t.u[0] = (unsigned)BPERM(idxq[i0],     (int)kpk01[mt][jg]);
                t.u[1] = (unsigned)BPERM(idxq[i0],     (int)kpk23[mt][jg]);
                t.u[2] = (unsigned)BPERM(idxq[i0 + 1], (int)kpk01[mt][jg]);
                t.u[3] = (unsigned)BPERM(idxq[i0 + 1], (int)kpk23[mt][jg]);
                ska[jt] = t.s;
            }
            // scores S^T tiles + softmax + P write
#pragma unroll
            for (int it = 0; it < 4; ++it) {
#pragma unroll
                for (int jt = 0; jt < 2; ++jt) {
                    f32x4 sacc = {0.f, 0.f, 0.f, 0.f};
                    sacc = MFMA(ska[jt], sqb[it], sacc, 0, 0, 0);
                    float e[4];
#pragma unroll
                    for (int r = 0; r < 4; ++r) {
                        const int j = jb * 32 + jt * 16 + q4 * 4 + r;
                        const bool allowed = (j <= iv[it]) || (j < aab);
                        float ee = exp2f(sacc[r]);
                        e[r] = allowed ? ee : 0.0f;
                    }
                    csum[it] += (e[0] + e[1]) + (e[2] + e[3]);
                    uint2 pw;
                    pw.x = pk2(e[0], e[1]);
                    pw.y = pk2(e[2], e[3]);
                    *(uint2*)&psl[w][iv[it]][jt * 16 + q4 * 4] = pw;
                }
            }
            // PV: O^T += V^T_slice @ P^T
            const int dcl = 8 * h + (l15 & 7);
            S8U av; av.v = *(const uint4*)&vbt[w][dcl][jb * 32 + q4 * 8];
#pragma unroll
            for (int it = 0; it < 4; ++it) {
                S8U pb; pb.v = *(const uint4*)&psl[w][iv[it]][q4 * 8];
                oacch[it] = MFMA(av.s, pb.s, oacch[it], 0, 0, 0);
            }
        }

        // col sums (full j range) + normalize
        float inv[4];
#pragma unroll
        for (int it = 0; it < 4; ++it) {
            float a = csum[it];
            a += __shfl_xor(a, 16, 64);
            a += __shfl_xor(a, 32, 64);
            inv[it] = 1.0f / a;
        }
        unsigned opk01[4], opk23[4];
#pragma unroll
        for (int it = 0; it < 4; ++it) {
            opk01[it] = pk2(oacch[it][0] * inv[it], oacch[it][1] * inv[it]);
            opk23[it] = pk2(oacch[it][2] * inv[it], oacch[it][3] * inv[it]);
        }
        // out-projection partial: Y += O_head @ Wp_head^T
#pragma unroll
        for (int mtile = 0; mtile < 4; ++mtile) {
            S8U t;
            t.u[0] = (unsigned)BPERM(idxq[0], (int)opk01[mtile]);
            t.u[1] = (unsigned)BPERM(idxq[0], (int)opk23[mtile]);
            t.u[2] = (unsigned)BPERM(idxq[1], (int)opk01[mtile]);
            t.u[3] = (unsigned)BPERM(idxq[1], (int)opk23[mtile]);
#pragma unroll
            for (int nt = 0; nt < 2; ++nt)
                yacc[mtile][nt] = MFMA(t.s, wpb[nt], yacc[mtile][nt], 0, 0, 0);
        }
    }

    // ---- store (f32) ----
    const float bpv[2] = { bp[l15], bp[16 + l15] };
    float* ob = out + (size_t)b * 64 * 32;
#pragma unroll
    for (int mt = 0; mt < 4; ++mt)
#pragma unroll
        for (int nt = 0; nt < 2; ++nt)
#pragma unroll
            for (int r = 0; r < 4; ++r)
                ob[(mt * 16 + q4 * 4 + r) * 32 + nt * 16 + l15] = yacc[mt][nt][r] + bpv[nt];
}

extern "C" void kernel_launch(void* const* d_in, const int* in_sizes, int n_in,
                              void* d_out, int out_size, void* d_ws, size_t ws_size,
                              hipStream_t stream) {
    const float* x  = (const float*)d_in[0];
    const int*   aa = (const int*)d_in[1];
    const float* Wq = (const float*)d_in[2];
    const float* bq = (const float*)d_in[3];
    const float* Wk = (const float*)d_in[4];
    const float* bk = (const float*)d_in[5];
    const float* Wv = (const float*)d_in[6];
    const float* bv = (const float*)d_in[7];
    const float* Wp = (const float*)d_in[8];
    const float* bp = (const float*)d_in[9];
    float* out = (float*)d_out;

    dim3 grid(NB / 2), block(128);
    hipLaunchKernelGGL(fused_attn_mfma, grid, block, 0, stream,
                       x, aa, Wq, bq, Wk, bk, Wv, bv, Wp, bp, out);
}

// Round 5
// 83.559 us; speedup vs baseline: 3.5918x; 1.5192x over previous
//
#include <hip/hip_runtime.h>
#include <cstdint>
#include <cstddef>

// Fused prefix-LM self-attention, B=8192, S=64, D=32, H=4, DH=8.
// 1 wave (64-thr block) per batch. bf16 MFMA 16x16x32 end-to-end.
// Q^T in registers (packed bf16, pre-scaled); K^T and V^T in LDS
// (score A-frags = broadcast ds_read_b128, garbage k>=8 killed by
// zeroed B-side); P redistributed through a tiny double-buffered LDS
// slice. Streaming softmax (no max subtraction, |score|<~2), col-sums
// via 2x shfl_xor. Mask folded to one compare: j <= max(i, aab-1).
#define NB 8192

typedef __attribute__((ext_vector_type(8))) short short8;
typedef __attribute__((ext_vector_type(4))) float f32x4;

union S8U { short8 s; unsigned u[4]; uint4 v; };

static __device__ __forceinline__ unsigned pk2(float a, float b) {
    unsigned short ua = __builtin_bit_cast(unsigned short, (__bf16)a);
    unsigned short ub = __builtin_bit_cast(unsigned short, (__bf16)b);
    return (unsigned)ua | ((unsigned)ub << 16);
}

#define MFMA __builtin_amdgcn_mfma_f32_16x16x32_bf16
#define BPERM __builtin_amdgcn_ds_bpermute
// compile-time memory fence: pins in-wave LDS write->read program order
// (DS pipe executes a wave's ops in order; only compiler motion must be stopped)
#define LDSFENCE() asm volatile("" ::: "memory")

__global__ __launch_bounds__(64, 3) void fused_attn_mfma(
    const float* __restrict__ x,
    const int*   __restrict__ aatt,
    const float* __restrict__ Wq, const float* __restrict__ bq,
    const float* __restrict__ Wk, const float* __restrict__ bk,
    const float* __restrict__ Wv, const float* __restrict__ bv,
    const float* __restrict__ Wp, const float* __restrict__ bp,
    float* __restrict__ out)
{
    __shared__ __align__(16) short klds[64][40];     // K[seq][dim], 80B rows (5120B)
    __shared__ __align__(16) short vbt[32][72];      // V^T[dim][seq], 144B rows (4608B)
    __shared__ __align__(16) short psl[2][16][40];   // P slice dbuf [i][j-local] (2560B)

    const int lane = threadIdx.x;          // 64 threads = 1 wave
    const int q4   = lane >> 4;
    const int l15  = lane & 15;
    const int b    = blockIdx.x;

    const int aab   = aatt[b];
    const int bmask = (q4 == 0) ? -1 : 0;
    const int idxq[4] = { l15*4, (l15+16)*4, (l15+32)*4, (l15+48)*4 };
    const int iv[4]   = { l15, 16+l15, 32+l15, 48+l15 };

    // allowed(j) == j <= max(i, aab-1); j = (compile-time C) + q4*4
    int cmpv[4];
#pragma unroll
    for (int it = 0; it < 4; ++it) cmpv[it] = max(iv[it], aab - 1) - q4*4;

    // ---- X fragments: row = tile*16+l15, k = q4*8+e ----
    short8 xa[4];
    const float* xb = x + (size_t)b * 64 * 32;
#pragma unroll
    for (int nt = 0; nt < 4; ++nt) {
        const float* p = xb + (nt*16 + l15)*32 + q4*8;
        float4 u0 = *(const float4*)p;
        float4 u1 = *(const float4*)(p + 4);
        S8U t;
        t.u[0] = pk2(u0.x, u0.y); t.u[1] = pk2(u0.z, u0.w);
        t.u[2] = pk2(u1.x, u1.y); t.u[3] = pk2(u1.z, u1.w);
        xa[nt] = t.s;
    }
    // bias column: 1.0 at k==32 (q4==0, e==0)
    S8U xo; xo.u[0] = (q4 == 0) ? 0x00003F80u : 0u; xo.u[1]=xo.u[2]=xo.u[3]=0u;
    const short8 xone = xo.s;

    auto wrow = [&](const float* W, int row) -> short8 {
        const float* p = W + row*32 + q4*8;
        float4 u0 = *(const float4*)p;
        float4 u1 = *(const float4*)(p + 4);
        S8U t;
        t.u[0] = pk2(u0.x, u0.y); t.u[1] = pk2(u0.z, u0.w);
        t.u[2] = pk2(u1.x, u1.y); t.u[3] = pk2(u1.z, u1.w);
        return t.s;
    };
    auto biasfrag = [&](const float* bb, int row) -> short8 {
        S8U t; t.u[0] = (q4 == 0) ? pk2(bb[row], 0.0f) : 0u;
        t.u[1]=t.u[2]=t.u[3]=0u;
        return t.s;
    };

    const float escale = 0.35355339059327373f * 1.4426950408889634f; // 1/sqrt(8)*log2(e)

    // ---- Q^T -> registers (packed bf16 pairs, pre-scaled) ----
    unsigned qpk01[2][4], qpk23[2][4];
#pragma unroll
    for (int mt = 0; mt < 2; ++mt) {
        short8 wa = wrow(Wq, mt*16 + l15);
        short8 wb = biasfrag(bq, mt*16 + l15);
#pragma unroll
        for (int nt = 0; nt < 4; ++nt) {
            f32x4 acc = {0.f,0.f,0.f,0.f};
            acc = MFMA(wa, xa[nt], acc, 0,0,0);
            acc = MFMA(wb, xone, acc, 0,0,0);
            qpk01[mt][nt] = pk2(acc[0]*escale, acc[1]*escale);
            qpk23[mt][nt] = pk2(acc[2]*escale, acc[3]*escale);
        }
    }
    // ---- K^T -> LDS K[seq][dim] ----
#pragma unroll
    for (int mt = 0; mt < 2; ++mt) {
        short8 wa = wrow(Wk, mt*16 + l15);
        short8 wb = biasfrag(bk, mt*16 + l15);
#pragma unroll
        for (int nt = 0; nt < 4; ++nt) {
            f32x4 acc = {0.f,0.f,0.f,0.f};
            acc = MFMA(wa, xa[nt], acc, 0,0,0);
            acc = MFMA(wb, xone, acc, 0,0,0);
            uint2 w2; w2.x = pk2(acc[0], acc[1]); w2.y = pk2(acc[2], acc[3]);
            *(uint2*)&klds[nt*16 + l15][mt*16 + q4*4] = w2;
        }
    }
    // ---- V -> LDS V^T[dim][seq] ----
#pragma unroll
    for (int nt = 0; nt < 2; ++nt) {
        short8 wv = wrow(Wv, nt*16 + l15);
        const float bvv = bv[nt*16 + l15];
#pragma unroll
        for (int mt = 0; mt < 4; ++mt) {
            f32x4 acc = {0.f,0.f,0.f,0.f};
            acc = MFMA(xa[mt], wv, acc, 0,0,0);
            uint2 w2;
            w2.x = pk2(acc[0]+bvv, acc[1]+bvv);
            w2.y = pk2(acc[2]+bvv, acc[3]+bvv);
            *(uint2*)&vbt[nt*16 + l15][mt*16 + q4*4] = w2;
        }
    }
    LDSFENCE();

    // ---- head loop ----
    f32x4 yacc[4][2];
#pragma unroll
    for (int mt = 0; mt < 4; ++mt)
#pragma unroll
        for (int nt = 0; nt < 2; ++nt) yacc[mt][nt] = (f32x4){0.f,0.f,0.f,0.f};

#pragma unroll
    for (int h = 0; h < 4; ++h) {
        const int mt = h >> 1;
        const int i0 = 2*(h & 1);

        // Q B-frags: zero k>=8 via bmask
        short8 sqb[4];
#pragma unroll
        for (int it = 0; it < 4; ++it) {
            S8U t;
            t.u[0] = (unsigned)BPERM(idxq[i0],   (int)qpk01[mt][it]) & (unsigned)bmask;
            t.u[1] = (unsigned)BPERM(idxq[i0],   (int)qpk23[mt][it]) & (unsigned)bmask;
            t.u[2] = (unsigned)BPERM(idxq[i0+1], (int)qpk01[mt][it]) & (unsigned)bmask;
            t.u[3] = (unsigned)BPERM(idxq[i0+1], (int)qpk23[mt][it]) & (unsigned)bmask;
            sqb[it] = t.s;
        }
        // Wp head-slice B-frags, zero k>=8
        short8 wpb[2];
#pragma unroll
        for (int nt = 0; nt < 2; ++nt) {
            const float* p = Wp + (nt*16 + l15)*32 + 8*h;
            float4 u0 = *(const float4*)p;
            float4 u1 = *(const float4*)(p + 4);
            S8U t;
            t.u[0] = pk2(u0.x,u0.y) & (unsigned)bmask;
            t.u[1] = pk2(u0.z,u0.w) & (unsigned)bmask;
            t.u[2] = pk2(u1.x,u1.y) & (unsigned)bmask;
            t.u[3] = pk2(u1.z,u1.w) & (unsigned)bmask;
            wpb[nt] = t.s;
        }

        float csum[4] = {0.f,0.f,0.f,0.f};
        f32x4 oacch[4];
#pragma unroll
        for (int it = 0; it < 4; ++it) oacch[it] = (f32x4){0.f,0.f,0.f,0.f};

#pragma unroll
        for (int jb = 0; jb < 2; ++jb) {
            // K A-frags: broadcast read (address q4-independent; k>=8 garbage
            // is multiplied by the zeroed B half)
            short8 ska[2];
#pragma unroll
            for (int jt = 0; jt < 2; ++jt) {
                S8U t; t.v = *(const uint4*)&klds[jb*32 + jt*16 + l15][8*h];
                ska[jt] = t.s;
            }
            // V^T A-frag for this head & j-half (rows duplicated across l15>=8)
            S8U av; av.v = *(const uint4*)&vbt[8*h + (l15 & 7)][jb*32 + q4*8];

#pragma unroll
            for (int it = 0; it < 4; ++it) {
#pragma unroll
                for (int jt = 0; jt < 2; ++jt) {
                    f32x4 sacc = {0.f,0.f,0.f,0.f};
                    sacc = MFMA(ska[jt], sqb[it], sacc, 0,0,0);
                    float e[4];
#pragma unroll
                    for (int r = 0; r < 4; ++r) {
                        float ee = exp2f(sacc[r]);
                        e[r] = (jb*32 + jt*16 + r <= cmpv[it]) ? ee : 0.0f;
                    }
                    csum[it] += (e[0]+e[1]) + (e[2]+e[3]);
                    uint2 pw; pw.x = pk2(e[0], e[1]); pw.y = pk2(e[2], e[3]);
                    *(uint2*)&psl[it & 1][l15][jt*16 + q4*4] = pw;
                }
                LDSFENCE();
                S8U pb; pb.v = *(const uint4*)&psl[it & 1][l15][q4*8];
                oacch[it] = MFMA(av.s, pb.s, oacch[it], 0,0,0);
            }
        }

        // column sums + normalize
        float inv[4];
#pragma unroll
        for (int it = 0; it < 4; ++it) {
            float a = csum[it];
            a += __shfl_xor(a, 16, 64);
            a += __shfl_xor(a, 32, 64);
            inv[it] = 1.0f / a;
        }
        unsigned opk01[4], opk23[4];
#pragma unroll
        for (int it = 0; it < 4; ++it) {
            opk01[it] = pk2(oacch[it][0]*inv[it], oacch[it][1]*inv[it]);
            opk23[it] = pk2(oacch[it][2]*inv[it], oacch[it][3]*inv[it]);
        }
        // out-projection partial: Y += O_head @ Wp_head^T
#pragma unroll
        for (int mtile = 0; mtile < 4; ++mtile) {
            S8U t;
            t.u[0] = (unsigned)BPERM(idxq[0], (int)opk01[mtile]);
            t.u[1] = (unsigned)BPERM(idxq[0], (int)opk23[mtile]);
            t.u[2] = (unsigned)BPERM(idxq[1], (int)opk01[mtile]);
            t.u[3] = (unsigned)BPERM(idxq[1], (int)opk23[mtile]);
#pragma unroll
            for (int nt = 0; nt < 2; ++nt)
                yacc[mtile][nt] = MFMA(t.s, wpb[nt], yacc[mtile][nt], 0,0,0);
        }
    }

    // ---- store (f32) ----
    const float bpv[2] = { bp[l15], bp[16 + l15] };
    float* ob = out + (size_t)b * 64 * 32;
#pragma unroll
    for (int mt = 0; mt < 4; ++mt)
#pragma unroll
        for (int nt = 0; nt < 2; ++nt)
#pragma unroll
            for (int r = 0; r < 4; ++r)
                ob[(mt*16 + q4*4 + r)*32 + nt*16 + l15] = yacc[mt][nt][r] + bpv[nt];
}

extern "C" void kernel_launch(void* const* d_in, const int* in_sizes, int n_in,
                              void* d_out, int out_size, void* d_ws, size_t ws_size,
                              hipStream_t stream) {
    const float* x  = (const float*)d_in[0];
    const int*   aa = (const int*)d_in[1];
    const float* Wq = (const float*)d_in[2];
    const float* bq = (const float*)d_in[3];
    const float* Wk = (const float*)d_in[4];
    const float* bk = (const float*)d_in[5];
    const float* Wv = (const float*)d_in[6];
    const float* bv = (const float*)d_in[7];
    const float* Wp = (const float*)d_in[8];
    const float* bp = (const float*)d_in[9];
    float* out = (float*)d_out;

    dim3 grid(NB), block(64);
    hipLaunchKernelGGL(fused_attn_mfma, grid, block, 0, stream,
                       x, aa, Wq, bq, Wk, bk, Wv, bv, Wp, bp, out);
}